// Round 1
// baseline (347.461 us; speedup 1.0000x reference)
//
#include <hip/hip_runtime.h>

#define B_ROWS 8192
#define IN_F 512
#define OUT_F 1024
#define K_TOT 1536

#define BM 128
#define BN 128
#define BK 64
#define LDST 72   // bf16 elems per LDS row: 64 + 8 pad (keeps 16B align for ds_read_b128)

typedef short bfrag __attribute__((ext_vector_type(8)));   // 8 bf16 = 4 VGPRs (guide §3)
typedef float f4    __attribute__((ext_vector_type(4)));

// round-to-nearest-even fp32 -> bf16, packed pairwise into a dword
__device__ __forceinline__ unsigned int pack2bf(float a, float b) {
    unsigned int ua = __float_as_uint(a);
    unsigned int ub = __float_as_uint(b);
    ua = (ua + 0x7fffu + ((ua >> 16) & 1u)) >> 16;
    ub = (ub + 0x7fffu + ((ub >> 16) & 1u)) & 0xffff0000u;
    return ua | ub;
}

__global__ __launch_bounds__(256, 2) void lsnn_step(
    const float* __restrict__ spikes,   // [B, 512]
    const float* __restrict__ zin,      // [B, 1024]
    const float* __restrict__ vin,      // [B, 1024]
    const float* __restrict__ iin,      // [B, 1024]
    const float* __restrict__ bin,      // [B, 1024]
    const float* __restrict__ Wi,       // [1024, 512]
    const float* __restrict__ Wr,       // [1024, 1024]
    float* __restrict__ out)            // [4, B, 1024]
{
    __shared__ unsigned short As[BM * LDST];
    __shared__ unsigned short Ws[BN * LDST];

    const int tid = threadIdx.x;
    const int bid = blockIdx.x;
    // n-major block swizzle: bid%8 -> n-tile, so each XCD reuses one W slice in L2
    const int n0 = (bid & 7) * BN;
    const int m0 = (bid >> 3) * BM;

    const int lane = tid & 63;
    const int wave = tid >> 6;
    const int wm = (wave >> 1) * 64;   // 2x2 wave grid over 128x128
    const int wn = (wave & 1) * 64;
    const int lr = lane & 15;          // A-frag row / B-frag col within 16
    const int lq = lane >> 4;          // quad -> k sub-offset / C row group

    // staging: 256 threads cover a 128x64 fp32 tile as 8 passes of 16 rows x 16 float4
    const int srow = tid >> 4;         // 0..15
    const int scol = (tid & 15) * 4;   // fp32 column group

    f4 acc[4][4];
    #pragma unroll
    for (int a = 0; a < 4; ++a)
        #pragma unroll
        for (int b = 0; b < 4; ++b)
            acc[a][b] = (f4)0.0f;

    for (int kt = 0; kt < K_TOT; kt += BK) {
        // BK=64 divides 512 and 1024: each tile comes wholly from one source
        const float* ap; const float* wp; int ast, wst;
        if (kt < IN_F) {
            ap = spikes + (size_t)m0 * IN_F + kt;            ast = IN_F;
            wp = Wi     + (size_t)n0 * IN_F + kt;            wst = IN_F;
        } else {
            ap = zin + (size_t)m0 * OUT_F + (kt - IN_F);     ast = OUT_F;
            wp = Wr  + (size_t)n0 * OUT_F + (kt - IN_F);     wst = OUT_F;
        }

        float4 fa[8], fw[8];
        #pragma unroll
        for (int p = 0; p < 8; ++p) {
            const int r = srow + p * 16;
            fa[p] = *(const float4*)(ap + (size_t)r * ast + scol);
            fw[p] = *(const float4*)(wp + (size_t)r * wst + scol);
        }
        __syncthreads();   // previous iteration's ds_reads must finish before overwrite
        #pragma unroll
        for (int p = 0; p < 8; ++p) {
            const int r = srow + p * 16;
            *(unsigned int*)&As[r * LDST + scol]     = pack2bf(fa[p].x, fa[p].y);
            *(unsigned int*)&As[r * LDST + scol + 2] = pack2bf(fa[p].z, fa[p].w);
            *(unsigned int*)&Ws[r * LDST + scol]     = pack2bf(fw[p].x, fw[p].y);
            *(unsigned int*)&Ws[r * LDST + scol + 2] = pack2bf(fw[p].z, fw[p].w);
        }
        __syncthreads();

        #pragma unroll
        for (int ks = 0; ks < 2; ++ks) {
            const int kk = ks * 32 + lq * 8;
            bfrag af[4], wf[4];
            #pragma unroll
            for (int t = 0; t < 4; ++t) {
                af[t] = *(const bfrag*)&As[(wm + t * 16 + lr) * LDST + kk];
                wf[t] = *(const bfrag*)&Ws[(wn + t * 16 + lr) * LDST + kk];
            }
            #pragma unroll
            for (int tm = 0; tm < 4; ++tm)
                #pragma unroll
                for (int tn = 0; tn < 4; ++tn)
                    acc[tm][tn] = __builtin_amdgcn_mfma_f32_16x16x32_bf16(
                        af[tm], wf[tn], acc[tm][tn], 0, 0, 0);
        }
    }

    // Epilogue: C/D mapping col = lane&15, row = (lane>>4)*4 + reg  (guide §3, m89/m91)
    const size_t PL = (size_t)B_ROWS * OUT_F;
    #pragma unroll
    for (int tm = 0; tm < 4; ++tm) {
        #pragma unroll
        for (int tn = 0; tn < 4; ++tn) {
            #pragma unroll
            for (int r = 0; r < 4; ++r) {
                const int gm = m0 + wm + tm * 16 + lq * 4 + r;
                const int gn = n0 + wn + tn * 16 + lr;
                const size_t idx = (size_t)gm * OUT_F + gn;
                const float v = vin[idx];
                const float i = iin[idx];
                const float b = bin[idx];
                // v_decayed = v + dt*tau_mem_inv*((v_leak - v) + i); dt*tau_mem_inv = 0.1
                const float v_dec = v + 0.1f * ((0.0f - v) + i);
                // i_decayed = i + dt*(-tau_syn_inv)*i; = i - 0.2*i
                const float i_dec = i + (-0.2f) * i;
                // b_decayed = b + dt*tau_adapt_inv*(v_th - b); dt/800 = 1.25e-6
                const float b_dec = b + 1.25e-06f * (1.0f - b);
                const float zn = (v_dec - b_dec > 0.0f) ? 1.0f : 0.0f;
                const float vn = (1.0f - zn) * v_dec;          // v_reset = 0
                const float inew = i_dec + acc[tm][tn][r];
                const float bnew = b_dec + zn * 0.00225f;      // tau_adapt_inv*beta = 1.8/800
                out[idx]          = zn;
                out[PL + idx]     = vn;
                out[2 * PL + idx] = inew;
                out[3 * PL + idx] = bnew;
            }
        }
    }
}

extern "C" void kernel_launch(void* const* d_in, const int* in_sizes, int n_in,
                              void* d_out, int out_size, void* d_ws, size_t ws_size,
                              hipStream_t stream) {
    const float* spikes = (const float*)d_in[0];
    const float* z      = (const float*)d_in[1];
    const float* v      = (const float*)d_in[2];
    const float* i      = (const float*)d_in[3];
    const float* b      = (const float*)d_in[4];
    const float* Wi     = (const float*)d_in[5];
    const float* Wr     = (const float*)d_in[6];
    float* out = (float*)d_out;

    const int grid = (B_ROWS / BM) * (OUT_F / BN);   // 64 * 8 = 512 blocks
    lsnn_step<<<grid, 256, 0, stream>>>(spikes, z, v, i, b, Wi, Wr, out);
}

// Round 2
// 316.890 us; speedup vs baseline: 1.0965x; 1.0965x over previous
//
#include <hip/hip_runtime.h>

#define B_ROWS 8192
#define IN_F 512
#define OUT_F 1024
#define K_TOT 1536

#define BM 64
#define BN 128
#define BK 64
#define LDST 72   // bf16 elems per LDS row: 64 + 8 pad (16B-aligned rows for ds_read_b128)
#define NITER (K_TOT / BK)   // 24

typedef short bfrag __attribute__((ext_vector_type(8)));   // 8 bf16 = 4 VGPRs
typedef float f4    __attribute__((ext_vector_type(4)));

// round-to-nearest-even fp32 -> bf16, packed pairwise into a dword
__device__ __forceinline__ unsigned int pack2bf(float a, float b) {
    unsigned int ua = __float_as_uint(a);
    unsigned int ub = __float_as_uint(b);
    ua = (ua + 0x7fffu + ((ua >> 16) & 1u)) >> 16;
    ub = (ub + 0x7fffu + ((ub >> 16) & 1u)) & 0xffff0000u;
    return ua | ub;
}

__global__ __launch_bounds__(256, 4) void lsnn_step(
    const float* __restrict__ spikes,   // [B, 512]
    const float* __restrict__ zin,      // [B, 1024]
    const float* __restrict__ vin,      // [B, 1024]
    const float* __restrict__ iin,      // [B, 1024]
    const float* __restrict__ bin,      // [B, 1024]
    const float* __restrict__ Wi,       // [1024, 512]
    const float* __restrict__ Wr,       // [1024, 1024]
    float* __restrict__ out)            // [4, B, 1024]
{
    __shared__ unsigned short As[BM * LDST];   // 9.2 KB
    __shared__ unsigned short Ws[BN * LDST];   // 18.4 KB

    const int tid = threadIdx.x;
    const int bid = blockIdx.x;
    // bid%8 -> n-tile: consecutive blocks (round-robin over XCDs) pin one W-slice per XCD L2
    const int n0 = (bid & 7) * BN;
    const int m0 = (bid >> 3) * BM;

    const int lane = tid & 63;
    const int wave = tid >> 6;
    const int wn = wave * 32;          // 1x4 wave grid: each wave = 64 rows x 32 cols
    const int lr = lane & 15;
    const int lq = lane >> 4;

    // staging: A tile 64x64 fp32 (4 float4/thread), W tile 128x64 fp32 (8 float4/thread)
    const int srow = tid >> 4;         // 0..15
    const int scol = (tid & 15) * 4;   // fp32 col group

    f4 acc[4][2];
    #pragma unroll
    for (int a = 0; a < 4; ++a)
        #pragma unroll
        for (int b = 0; b < 2; ++b)
            acc[a][b] = (f4)0.0f;

    float4 fa[4], fw[8];               // register prefetch buffers

    auto load_tile = [&](int kt) {
        const float* ap; const float* wp; int ast, wst;
        if (kt < IN_F) {
            ap = spikes + (size_t)m0 * IN_F + kt;          ast = IN_F;
            wp = Wi     + (size_t)n0 * IN_F + kt;          wst = IN_F;
        } else {
            ap = zin + (size_t)m0 * OUT_F + (kt - IN_F);   ast = OUT_F;
            wp = Wr  + (size_t)n0 * OUT_F + (kt - IN_F);   wst = OUT_F;
        }
        #pragma unroll
        for (int p = 0; p < 4; ++p)
            fa[p] = *(const float4*)(ap + (size_t)(srow + p * 16) * ast + scol);
        #pragma unroll
        for (int p = 0; p < 8; ++p)
            fw[p] = *(const float4*)(wp + (size_t)(srow + p * 16) * wst + scol);
    };

    load_tile(0);

    for (int it = 0; it < NITER; ++it) {
        __syncthreads();   // previous iteration's ds_reads done before overwrite
        // convert + store to LDS (compiler waits vmcnt here — loads had a full
        // MFMA phase to land)
        #pragma unroll
        for (int p = 0; p < 4; ++p) {
            uint2 pk = { pack2bf(fa[p].x, fa[p].y), pack2bf(fa[p].z, fa[p].w) };
            *(uint2*)&As[(srow + p * 16) * LDST + scol] = pk;
        }
        #pragma unroll
        for (int p = 0; p < 8; ++p) {
            uint2 pk = { pack2bf(fw[p].x, fw[p].y), pack2bf(fw[p].z, fw[p].w) };
            *(uint2*)&Ws[(srow + p * 16) * LDST + scol] = pk;
        }
        __syncthreads();

        // issue next tile's global loads NOW — they fly during the MFMA phase
        if (it + 1 < NITER) load_tile((it + 1) * BK);

        #pragma unroll
        for (int ks = 0; ks < 2; ++ks) {
            const int kk = ks * 32 + lq * 8;
            bfrag af[4], wf[2];
            #pragma unroll
            for (int t = 0; t < 4; ++t)
                af[t] = *(const bfrag*)&As[(t * 16 + lr) * LDST + kk];
            #pragma unroll
            for (int t = 0; t < 2; ++t)
                wf[t] = *(const bfrag*)&Ws[(wn + t * 16 + lr) * LDST + kk];
            #pragma unroll
            for (int tm = 0; tm < 4; ++tm)
                #pragma unroll
                for (int tn = 0; tn < 2; ++tn)
                    acc[tm][tn] = __builtin_amdgcn_mfma_f32_16x16x32_bf16(
                        af[tm], wf[tn], acc[tm][tn], 0, 0, 0);
        }
    }

    // Epilogue: C/D mapping col = lane&15, row = (lane>>4)*4 + reg (guide §3, m89/m91)
    const size_t PL = (size_t)B_ROWS * OUT_F;
    #pragma unroll
    for (int tm = 0; tm < 4; ++tm) {
        #pragma unroll
        for (int tn = 0; tn < 2; ++tn) {
            #pragma unroll
            for (int r = 0; r < 4; ++r) {
                const int gm = m0 + tm * 16 + lq * 4 + r;
                const int gn = n0 + wn + tn * 16 + lr;
                const size_t idx = (size_t)gm * OUT_F + gn;
                const float v = vin[idx];
                const float i = iin[idx];
                const float b = bin[idx];
                const float v_dec = v + 0.1f * ((0.0f - v) + i);       // dt*tau_mem_inv = 0.1
                const float i_dec = i - 0.2f * i;                      // dt*tau_syn_inv = 0.2
                const float b_dec = b + 1.25e-06f * (1.0f - b);        // dt*tau_adapt_inv
                const float zn = (v_dec - b_dec > 0.0f) ? 1.0f : 0.0f;
                const float vn = (1.0f - zn) * v_dec;                  // v_reset = 0
                const float inew = i_dec + acc[tm][tn][r];
                const float bnew = b_dec + zn * 0.00225f;              // tau_adapt_inv*beta
                out[idx]          = zn;
                out[PL + idx]     = vn;
                out[2 * PL + idx] = inew;
                out[3 * PL + idx] = bnew;
            }
        }
    }
}

extern "C" void kernel_launch(void* const* d_in, const int* in_sizes, int n_in,
                              void* d_out, int out_size, void* d_ws, size_t ws_size,
                              hipStream_t stream) {
    const float* spikes = (const float*)d_in[0];
    const float* z      = (const float*)d_in[1];
    const float* v      = (const float*)d_in[2];
    const float* i      = (const float*)d_in[3];
    const float* b      = (const float*)d_in[4];
    const float* Wi     = (const float*)d_in[5];
    const float* Wr     = (const float*)d_in[6];
    float* out = (float*)d_out;

    const int grid = (B_ROWS / BM) * (OUT_F / BN);   // 128 * 8 = 1024 blocks
    lsnn_step<<<grid, 256, 0, stream>>>(spikes, z, v, i, b, Wi, Wr, out);
}